// Round 1
// baseline (2120.339 us; speedup 1.0000x reference)
//
#include <hip/hip_runtime.h>
#include <math.h>

// Problem constants
#define NBATCH 4
#define TDIM 2048
#define DDIM 1024

// GEMM tiling: 128x128 block tile, 256 threads, 8x8 micro-tile/thread, BK=16
#define BM 128
#define BN 128
#define BK 16
#define NTHREADS 256

// ---------------------------------------------------------------------------
// Kernel 1: QKV projection.  C[m][n] = sum_k X[m][k] * W[n][k]
// M = 8192 (b*t), N = 3072 (3d), K = 1024.  Both operands k-contiguous (NT).
// Epilogue de-interleaves column e -> (c = e%3, i = e/3) into q/k/v buffers.
// ---------------------------------------------------------------------------
__global__ __launch_bounds__(NTHREADS) void qkv_gemm(
    const float* __restrict__ A, const float* __restrict__ Bmat,
    float* __restrict__ q, float* __restrict__ k, float* __restrict__ v) {
  __shared__ __align__(16) float As[BK][BM + 4];
  __shared__ __align__(16) float Bs[BK][BN + 4];
  const int tid = threadIdx.x;
  const int m0 = blockIdx.y * BM;
  const int n0 = blockIdx.x * BN;
  const int tx = tid & 15, ty = tid >> 4;
  const int K = DDIM;

  float acc[8][8];
#pragma unroll
  for (int i = 0; i < 8; ++i)
#pragma unroll
    for (int j = 0; j < 8; ++j) acc[i][j] = 0.f;

  for (int kt = 0; kt < K; kt += BK) {
#pragma unroll
    for (int r = 0; r < 2; ++r) {
      int f = tid + r * 256;
      int m = f >> 2, kq = f & 3;
      float4 av = *reinterpret_cast<const float4*>(&A[(size_t)(m0 + m) * DDIM + kt + kq * 4]);
      As[kq * 4 + 0][m] = av.x; As[kq * 4 + 1][m] = av.y;
      As[kq * 4 + 2][m] = av.z; As[kq * 4 + 3][m] = av.w;
      float4 bv = *reinterpret_cast<const float4*>(&Bmat[(size_t)(n0 + m) * DDIM + kt + kq * 4]);
      Bs[kq * 4 + 0][m] = bv.x; Bs[kq * 4 + 1][m] = bv.y;
      Bs[kq * 4 + 2][m] = bv.z; Bs[kq * 4 + 3][m] = bv.w;
    }
    __syncthreads();
#pragma unroll
    for (int kk = 0; kk < BK; ++kk) {
      float4 a0 = *reinterpret_cast<const float4*>(&As[kk][ty * 4]);
      float4 a1 = *reinterpret_cast<const float4*>(&As[kk][ty * 4 + 64]);
      float4 b0 = *reinterpret_cast<const float4*>(&Bs[kk][tx * 4]);
      float4 b1 = *reinterpret_cast<const float4*>(&Bs[kk][tx * 4 + 64]);
      float aa[8] = {a0.x, a0.y, a0.z, a0.w, a1.x, a1.y, a1.z, a1.w};
      float bb[8] = {b0.x, b0.y, b0.z, b0.w, b1.x, b1.y, b1.z, b1.w};
#pragma unroll
      for (int i = 0; i < 8; ++i)
#pragma unroll
        for (int j = 0; j < 8; ++j) acc[i][j] = fmaf(aa[i], bb[j], acc[i][j]);
    }
    __syncthreads();
  }

#pragma unroll
  for (int i = 0; i < 8; ++i) {
    int row = m0 + ((i < 4) ? ty * 4 + i : 64 + ty * 4 + (i - 4));
#pragma unroll
    for (int j = 0; j < 8; ++j) {
      int col = n0 + ((j < 4) ? tx * 4 + j : 64 + tx * 4 + (j - 4));
      int c = col % 3;
      int ii = col / 3;
      float* dst = (c == 0) ? q : (c == 1) ? k : v;
      dst[(size_t)row * DDIM + ii] = acc[i][j];
    }
  }
}

// ---------------------------------------------------------------------------
// Kernel 2: scores.  S[i][j] = scale * sum_k Q[i][k]*K[j][k]   (NT)
// M = N = 2048, K = 1024
// ---------------------------------------------------------------------------
__global__ __launch_bounds__(NTHREADS) void score_gemm(
    const float* __restrict__ A, const float* __restrict__ Bmat,
    float* __restrict__ S) {
  __shared__ __align__(16) float As[BK][BM + 4];
  __shared__ __align__(16) float Bs[BK][BN + 4];
  const int tid = threadIdx.x;
  const int m0 = blockIdx.y * BM;
  const int n0 = blockIdx.x * BN;
  const int tx = tid & 15, ty = tid >> 4;
  const int K = DDIM;

  float acc[8][8];
#pragma unroll
  for (int i = 0; i < 8; ++i)
#pragma unroll
    for (int j = 0; j < 8; ++j) acc[i][j] = 0.f;

  for (int kt = 0; kt < K; kt += BK) {
#pragma unroll
    for (int r = 0; r < 2; ++r) {
      int f = tid + r * 256;
      int m = f >> 2, kq = f & 3;
      float4 av = *reinterpret_cast<const float4*>(&A[(size_t)(m0 + m) * DDIM + kt + kq * 4]);
      As[kq * 4 + 0][m] = av.x; As[kq * 4 + 1][m] = av.y;
      As[kq * 4 + 2][m] = av.z; As[kq * 4 + 3][m] = av.w;
      float4 bv = *reinterpret_cast<const float4*>(&Bmat[(size_t)(n0 + m) * DDIM + kt + kq * 4]);
      Bs[kq * 4 + 0][m] = bv.x; Bs[kq * 4 + 1][m] = bv.y;
      Bs[kq * 4 + 2][m] = bv.z; Bs[kq * 4 + 3][m] = bv.w;
    }
    __syncthreads();
#pragma unroll
    for (int kk = 0; kk < BK; ++kk) {
      float4 a0 = *reinterpret_cast<const float4*>(&As[kk][ty * 4]);
      float4 a1 = *reinterpret_cast<const float4*>(&As[kk][ty * 4 + 64]);
      float4 b0 = *reinterpret_cast<const float4*>(&Bs[kk][tx * 4]);
      float4 b1 = *reinterpret_cast<const float4*>(&Bs[kk][tx * 4 + 64]);
      float aa[8] = {a0.x, a0.y, a0.z, a0.w, a1.x, a1.y, a1.z, a1.w};
      float bb[8] = {b0.x, b0.y, b0.z, b0.w, b1.x, b1.y, b1.z, b1.w};
#pragma unroll
      for (int i = 0; i < 8; ++i)
#pragma unroll
        for (int j = 0; j < 8; ++j) acc[i][j] = fmaf(aa[i], bb[j], acc[i][j]);
    }
    __syncthreads();
  }

  const float scale = 0.03125f;  // 1/sqrt(1024)
#pragma unroll
  for (int i = 0; i < 8; ++i) {
    int row = m0 + ((i < 4) ? ty * 4 + i : 64 + ty * 4 + (i - 4));
    float4 w0, w1;
    w0.x = acc[i][0] * scale; w0.y = acc[i][1] * scale;
    w0.z = acc[i][2] * scale; w0.w = acc[i][3] * scale;
    w1.x = acc[i][4] * scale; w1.y = acc[i][5] * scale;
    w1.z = acc[i][6] * scale; w1.w = acc[i][7] * scale;
    *reinterpret_cast<float4*>(&S[(size_t)row * TDIM + n0 + tx * 4]) = w0;
    *reinterpret_cast<float4*>(&S[(size_t)row * TDIM + n0 + 64 + tx * 4]) = w1;
  }
}

// ---------------------------------------------------------------------------
// Kernel 3: row softmax, in place.  One block per row, 2048 elements.
// ---------------------------------------------------------------------------
__global__ __launch_bounds__(NTHREADS) void softmax_rows(float* __restrict__ S) {
  __shared__ float redm[4];
  __shared__ float reds[4];
  const int tid = threadIdx.x;
  float* p = S + (size_t)blockIdx.x * TDIM;
  float4 x0 = reinterpret_cast<const float4*>(p)[tid];
  float4 x1 = reinterpret_cast<const float4*>(p)[tid + 256];

  float m = fmaxf(fmaxf(fmaxf(x0.x, x0.y), fmaxf(x0.z, x0.w)),
                  fmaxf(fmaxf(x1.x, x1.y), fmaxf(x1.z, x1.w)));
#pragma unroll
  for (int off = 32; off > 0; off >>= 1) m = fmaxf(m, __shfl_down(m, off, 64));
  int wave = tid >> 6, lane = tid & 63;
  if (lane == 0) redm[wave] = m;
  __syncthreads();
  m = fmaxf(fmaxf(redm[0], redm[1]), fmaxf(redm[2], redm[3]));

  x0.x = expf(x0.x - m); x0.y = expf(x0.y - m);
  x0.z = expf(x0.z - m); x0.w = expf(x0.w - m);
  x1.x = expf(x1.x - m); x1.y = expf(x1.y - m);
  x1.z = expf(x1.z - m); x1.w = expf(x1.w - m);
  float s = x0.x + x0.y + x0.z + x0.w + x1.x + x1.y + x1.z + x1.w;
#pragma unroll
  for (int off = 32; off > 0; off >>= 1) s += __shfl_down(s, off, 64);
  if (lane == 0) reds[wave] = s;
  __syncthreads();
  s = reds[0] + reds[1] + reds[2] + reds[3];
  float inv = 1.0f / s;

  x0.x *= inv; x0.y *= inv; x0.z *= inv; x0.w *= inv;
  x1.x *= inv; x1.y *= inv; x1.z *= inv; x1.w *= inv;
  reinterpret_cast<float4*>(p)[tid] = x0;
  reinterpret_cast<float4*>(p)[tid + 256] = x1;
}

// ---------------------------------------------------------------------------
// Kernel 4: out = P * V   (NN).  M = 2048, N = 1024, K = 2048.
// A (P) k-contiguous; B (V) n-contiguous (direct-copy LDS staging).
// ---------------------------------------------------------------------------
__global__ __launch_bounds__(NTHREADS) void pv_gemm(
    const float* __restrict__ P, const float* __restrict__ V,
    float* __restrict__ out) {
  __shared__ __align__(16) float As[BK][BM + 4];
  __shared__ __align__(16) float Bs[BK][BN + 4];
  const int tid = threadIdx.x;
  const int m0 = blockIdx.y * BM;
  const int n0 = blockIdx.x * BN;
  const int tx = tid & 15, ty = tid >> 4;
  const int K = TDIM;

  float acc[8][8];
#pragma unroll
  for (int i = 0; i < 8; ++i)
#pragma unroll
    for (int j = 0; j < 8; ++j) acc[i][j] = 0.f;

  for (int kt = 0; kt < K; kt += BK) {
#pragma unroll
    for (int r = 0; r < 2; ++r) {
      int f = tid + r * 256;
      int m = f >> 2, kq = f & 3;
      float4 av = *reinterpret_cast<const float4*>(&P[(size_t)(m0 + m) * TDIM + kt + kq * 4]);
      As[kq * 4 + 0][m] = av.x; As[kq * 4 + 1][m] = av.y;
      As[kq * 4 + 2][m] = av.z; As[kq * 4 + 3][m] = av.w;
      int krow = f >> 5, n4 = f & 31;
      float4 bv = *reinterpret_cast<const float4*>(&V[(size_t)(kt + krow) * DDIM + n0 + n4 * 4]);
      *reinterpret_cast<float4*>(&Bs[krow][n4 * 4]) = bv;
    }
    __syncthreads();
#pragma unroll
    for (int kk = 0; kk < BK; ++kk) {
      float4 a0 = *reinterpret_cast<const float4*>(&As[kk][ty * 4]);
      float4 a1 = *reinterpret_cast<const float4*>(&As[kk][ty * 4 + 64]);
      float4 b0 = *reinterpret_cast<const float4*>(&Bs[kk][tx * 4]);
      float4 b1 = *reinterpret_cast<const float4*>(&Bs[kk][tx * 4 + 64]);
      float aa[8] = {a0.x, a0.y, a0.z, a0.w, a1.x, a1.y, a1.z, a1.w};
      float bb[8] = {b0.x, b0.y, b0.z, b0.w, b1.x, b1.y, b1.z, b1.w};
#pragma unroll
      for (int i = 0; i < 8; ++i)
#pragma unroll
        for (int j = 0; j < 8; ++j) acc[i][j] = fmaf(aa[i], bb[j], acc[i][j]);
    }
    __syncthreads();
  }

#pragma unroll
  for (int i = 0; i < 8; ++i) {
    int row = m0 + ((i < 4) ? ty * 4 + i : 64 + ty * 4 + (i - 4));
    float4 w0, w1;
    w0.x = acc[i][0]; w0.y = acc[i][1]; w0.z = acc[i][2]; w0.w = acc[i][3];
    w1.x = acc[i][4]; w1.y = acc[i][5]; w1.z = acc[i][6]; w1.w = acc[i][7];
    *reinterpret_cast<float4*>(&out[(size_t)row * DDIM + n0 + tx * 4]) = w0;
    *reinterpret_cast<float4*>(&out[(size_t)row * DDIM + n0 + 64 + tx * 4]) = w1;
  }
}

// ---------------------------------------------------------------------------
extern "C" void kernel_launch(void* const* d_in, const int* in_sizes, int n_in,
                              void* d_out, int out_size, void* d_ws, size_t ws_size,
                              hipStream_t stream) {
  const float* x = (const float*)d_in[0];      // [4, 2048, 1024]
  const float* W = (const float*)d_in[1];      // [3072, 1024]
  float* out = (float*)d_out;                  // [4, 2048, 1024]

  float* ws = (float*)d_ws;
  const size_t btd = (size_t)NBATCH * TDIM * DDIM;  // 8.39M floats
  float* q = ws;
  float* k = q + btd;
  float* v = k + btd;
  float* S = v + btd;  // 2048*2048 floats, reused per batch (ws total ~112 MB)

  dim3 blk(NTHREADS);

  // QKV projection: grid 24 x 64
  qkv_gemm<<<dim3((3 * DDIM) / BN, (NBATCH * TDIM) / BM), blk, 0, stream>>>(x, W, q, k, v);

  for (int b = 0; b < NBATCH; ++b) {
    const size_t off = (size_t)b * TDIM * DDIM;
    score_gemm<<<dim3(TDIM / BN, TDIM / BM), blk, 0, stream>>>(q + off, k + off, S);
    softmax_rows<<<dim3(TDIM), blk, 0, stream>>>(S);
    pv_gemm<<<dim3(DDIM / BN, TDIM / BM), blk, 0, stream>>>(S, v + off, out + off);
  }
}

// Round 2
// 285.235 us; speedup vs baseline: 7.4337x; 7.4337x over previous
//
#include <hip/hip_runtime.h>
#include <math.h>

#define NBATCH 4
#define TDIM 2048
#define DDIM 1024

typedef __attribute__((ext_vector_type(8))) short short8;     // 8 bf16 MFMA frag
typedef __attribute__((ext_vector_type(4))) float floatx4;    // MFMA acc
typedef __attribute__((ext_vector_type(8))) unsigned short ushort8;
typedef __attribute__((ext_vector_type(4))) unsigned short ushort4v;

__device__ __forceinline__ unsigned short f2bf(float f) {
  unsigned int u = __float_as_uint(f);
  u += 0x7fffu + ((u >> 16) & 1u);   // round-to-nearest-even
  return (unsigned short)(u >> 16);
}
__device__ __forceinline__ float bf2f(unsigned short h) {
  return __uint_as_float(((unsigned int)h) << 16);
}

// async 16B global -> LDS (HW scatters lane i to lptr + i*16)
__device__ __forceinline__ void gload_lds16(const ushort* g, ushort* l) {
  __builtin_amdgcn_global_load_lds(
      (const __attribute__((address_space(1))) void*)g,
      (__attribute__((address_space(3))) void*)l, 16, 0, 0);
}

// ---------------------------------------------------------------------------
// Shared MFMA GEMM core: C[128x128] block at (Abase rows, Bbase rows), NT:
// C[m][n] += sum_k A[m][k] * B[n][k], both K-contiguous bf16 (ushort).
// 256 threads = 4 waves; wave (wm,wn) owns a 64x64 quadrant as 4x4 MFMA tiles.
// LDS tiles [128 rows][32 k] bf16, 16B-chunk XOR swizzle (slot = kc ^ (row&3))
// so global_load_lds's linear lane*16 placement is compatible (no padding) and
// ds_read_b128 conflicts drop from 8-way to 4-way.
// ---------------------------------------------------------------------------
__device__ __forceinline__ void mfma_gemm_core(
    const ushort* __restrict__ Abase, const ushort* __restrict__ Bbase,
    int lda, int ldb, int K, ushort* As, ushort* Bs, floatx4 acc[4][4]) {
  const int tid = threadIdx.x;
  const int wave = tid >> 6;
  const int lane = tid & 63;
  const int l15 = lane & 15;
  const int quad = lane >> 4;
  const int wm = wave >> 1, wn = wave & 1;

  // staging: wave stages rows [32*wave, 32*wave+32), 2 insts of 16 rows each.
  // lane l -> row = rbase + l/4, LDS slot l&3; source chunk = (l&3) ^ (row&3).
  const int srow0 = wave * 32 + (lane >> 2);
  const int srow1 = srow0 + 16;
  const int skc = (lane & 3) ^ ((lane >> 2) & 3);
  const ushort* agp0 = Abase + (size_t)srow0 * lda + skc * 8;
  const ushort* agp1 = Abase + (size_t)srow1 * lda + skc * 8;
  const ushort* bgp0 = Bbase + (size_t)srow0 * ldb + skc * 8;
  const ushort* bgp1 = Bbase + (size_t)srow1 * ldb + skc * 8;
  ushort* al0 = As + (size_t)(wave * 32) * 32;
  ushort* al1 = As + (size_t)(wave * 32 + 16) * 32;
  ushort* bl0 = Bs + (size_t)(wave * 32) * 32;
  ushort* bl1 = Bs + (size_t)(wave * 32 + 16) * 32;

  // compute-side: logical chunk quad lives in slot quad ^ (row&3); row&3 == l15&3
  const int rchunk = quad ^ (l15 & 3);
  int aoff[4], boff[4];
#pragma unroll
  for (int t = 0; t < 4; ++t) {
    aoff[t] = (wm * 64 + t * 16 + l15) * 32 + rchunk * 8;
    boff[t] = (wn * 64 + t * 16 + l15) * 32 + rchunk * 8;
  }

  for (int kt = 0; kt < K; kt += 32) {
    gload_lds16(agp0 + kt, al0);
    gload_lds16(agp1 + kt, al1);
    gload_lds16(bgp0 + kt, bl0);
    gload_lds16(bgp1 + kt, bl1);
    __syncthreads();   // vmcnt(0) drain + barrier: staged tiles visible
    short8 af[4], bfr[4];
#pragma unroll
    for (int t = 0; t < 4; ++t) {
      af[t] = *(const short8*)&As[aoff[t]];
      bfr[t] = *(const short8*)&Bs[boff[t]];
    }
#pragma unroll
    for (int i = 0; i < 4; ++i)
#pragma unroll
      for (int j = 0; j < 4; ++j)
        acc[i][j] = __builtin_amdgcn_mfma_f32_16x16x32_bf16(af[i], bfr[j], acc[i][j], 0, 0, 0);
    __syncthreads();   // protect LDS from next iter's staging
  }
}

// ---------------------------------------------------------------------------
// Converts
// ---------------------------------------------------------------------------
__global__ __launch_bounds__(256) void convert_x(const float* __restrict__ x,
                                                 ushort* __restrict__ xb) {
  const size_t i = (size_t)blockIdx.x * 256 + threadIdx.x;  // float4 index
  float4 v = reinterpret_cast<const float4*>(x)[i];
  ushort4v h = {f2bf(v.x), f2bf(v.y), f2bf(v.z), f2bf(v.w)};
  reinterpret_cast<ushort4v*>(xb)[i] = h;
}

// W row e -> dst row (e%3)*1024 + e/3; q-rows (e%3==0) pre-scaled by 1/32 (exact)
__global__ __launch_bounds__(256) void convert_w(const float* __restrict__ W,
                                                 ushort* __restrict__ wb) {
  const int e = blockIdx.x;
  const int c = e % 3, ii = e / 3;
  const float scale = (c == 0) ? 0.03125f : 1.0f;
  const float4 v = reinterpret_cast<const float4*>(W + (size_t)e * DDIM)[threadIdx.x];
  ushort4v h = {f2bf(v.x * scale), f2bf(v.y * scale), f2bf(v.z * scale), f2bf(v.w * scale)};
  reinterpret_cast<ushort4v*>(wb + (size_t)(c * DDIM + ii) * DDIM)[threadIdx.x] = h;
}

// ---------------------------------------------------------------------------
// QKV projection: [8192 x 3072] = xb[8192x1024] * wb[3072x1024]^T.
// wb rows are permuted (q|k|v blocks), so each 128-col block is pure q, k or v.
// q,k written row-major bf16; v written transposed [b][d][t] (for PV's NT).
// ---------------------------------------------------------------------------
__global__ __launch_bounds__(256) void qkv_gemm(
    const ushort* __restrict__ xb, const ushort* __restrict__ wb,
    ushort* __restrict__ qb, ushort* __restrict__ kb, ushort* __restrict__ vt) {
  __shared__ __align__(16) ushort As[128 * 32];
  __shared__ __align__(16) ushort Bs[128 * 32];
  const int m0 = blockIdx.y * 128;
  const int n0 = blockIdx.x * 128;
  floatx4 acc[4][4];
  const floatx4 z4 = {0.f, 0.f, 0.f, 0.f};
#pragma unroll
  for (int i = 0; i < 4; ++i)
#pragma unroll
    for (int j = 0; j < 4; ++j) acc[i][j] = z4;

  mfma_gemm_core(xb + (size_t)m0 * DDIM, wb + (size_t)n0 * DDIM, DDIM, DDIM,
                 DDIM, As, Bs, acc);

  const int tid = threadIdx.x;
  const int wave = tid >> 6, lane = tid & 63;
  const int l15 = lane & 15, quad = lane >> 4;
  const int wm = wave >> 1, wn = wave & 1;

  if (n0 < 2 * DDIM) {
    ushort* dst = (n0 < DDIM) ? qb : kb;
    const int cb = (n0 < DDIM) ? n0 : n0 - DDIM;
#pragma unroll
    for (int i = 0; i < 4; ++i) {
      const int rbase = m0 + wm * 64 + i * 16 + quad * 4;
#pragma unroll
      for (int j = 0; j < 4; ++j) {
        const int col = cb + wn * 64 + j * 16 + l15;
#pragma unroll
        for (int r = 0; r < 4; ++r)
          dst[(size_t)(rbase + r) * DDIM + col] = f2bf(acc[i][j][r]);
      }
    }
  } else {
#pragma unroll
    for (int i = 0; i < 4; ++i) {
      const int row = m0 + wm * 64 + i * 16 + quad * 4;  // 4 consecutive t
      const int b = row >> 11, t = row & (TDIM - 1);
#pragma unroll
      for (int j = 0; j < 4; ++j) {
        const int d = (n0 - 2 * DDIM) + wn * 64 + j * 16 + l15;
        ushort4v pk = {f2bf(acc[i][j][0]), f2bf(acc[i][j][1]),
                       f2bf(acc[i][j][2]), f2bf(acc[i][j][3])};
        *reinterpret_cast<ushort4v*>(
            &vt[(size_t)((b << 10) + d) * TDIM + t]) = pk;
      }
    }
  }
}

// ---------------------------------------------------------------------------
// Scores: per batch z, S[i][j] = q_scaled[i]·k[j]  (scale folded into q rows)
// ---------------------------------------------------------------------------
__global__ __launch_bounds__(256) void score_gemm(
    const ushort* __restrict__ qb, const ushort* __restrict__ kb,
    ushort* __restrict__ Sb) {
  __shared__ __align__(16) ushort As[128 * 32];
  __shared__ __align__(16) ushort Bs[128 * 32];
  const int z = blockIdx.z;
  const int m0 = blockIdx.y * 128;
  const int n0 = blockIdx.x * 128;
  floatx4 acc[4][4];
  const floatx4 z4 = {0.f, 0.f, 0.f, 0.f};
#pragma unroll
  for (int i = 0; i < 4; ++i)
#pragma unroll
    for (int j = 0; j < 4; ++j) acc[i][j] = z4;

  mfma_gemm_core(qb + ((size_t)z * TDIM + m0) * DDIM,
                 kb + ((size_t)z * TDIM + n0) * DDIM, DDIM, DDIM, DDIM, As, Bs,
                 acc);

  const int tid = threadIdx.x;
  const int wave = tid >> 6, lane = tid & 63;
  const int l15 = lane & 15, quad = lane >> 4;
  const int wm = wave >> 1, wn = wave & 1;
  ushort* S = Sb + (size_t)z * TDIM * TDIM;
#pragma unroll
  for (int i = 0; i < 4; ++i) {
    const int rbase = m0 + wm * 64 + i * 16 + quad * 4;
#pragma unroll
    for (int j = 0; j < 4; ++j) {
      const int col = n0 + wn * 64 + j * 16 + l15;
#pragma unroll
      for (int r = 0; r < 4; ++r)
        S[(size_t)(rbase + r) * TDIM + col] = f2bf(acc[i][j][r]);
    }
  }
}

// ---------------------------------------------------------------------------
// Row softmax over bf16 scores, in place (row-local, no cross-row overlap).
// ---------------------------------------------------------------------------
__global__ __launch_bounds__(256) void softmax_rows(ushort* __restrict__ Sb) {
  __shared__ float redm[4], reds[4];
  const int tid = threadIdx.x;
  ushort* p = Sb + (size_t)blockIdx.x * TDIM;
  ushort8 hv = *reinterpret_cast<const ushort8*>(&p[tid * 8]);
  float x[8];
#pragma unroll
  for (int e = 0; e < 8; ++e) x[e] = bf2f(hv[e]);

  float m = x[0];
#pragma unroll
  for (int e = 1; e < 8; ++e) m = fmaxf(m, x[e]);
#pragma unroll
  for (int off = 32; off > 0; off >>= 1) m = fmaxf(m, __shfl_down(m, off, 64));
  const int wave = tid >> 6, lane = tid & 63;
  if (lane == 0) redm[wave] = m;
  __syncthreads();
  m = fmaxf(fmaxf(redm[0], redm[1]), fmaxf(redm[2], redm[3]));

  float s = 0.f;
#pragma unroll
  for (int e = 0; e < 8; ++e) {
    x[e] = __expf(x[e] - m);
    s += x[e];
  }
#pragma unroll
  for (int off = 32; off > 0; off >>= 1) s += __shfl_down(s, off, 64);
  if (lane == 0) reds[wave] = s;
  __syncthreads();
  s = reds[0] + reds[1] + reds[2] + reds[3];
  const float inv = 1.0f / s;
#pragma unroll
  for (int e = 0; e < 8; ++e) hv[e] = f2bf(x[e] * inv);
  *reinterpret_cast<ushort8*>(&p[tid * 8]) = hv;
}

// ---------------------------------------------------------------------------
// PV: out[t][d] = sum_j P[t][j] * vt[d][j]  (NT, both K-contiguous bf16)
// ---------------------------------------------------------------------------
__global__ __launch_bounds__(256) void pv_gemm(
    const ushort* __restrict__ Pb, const ushort* __restrict__ vt,
    float* __restrict__ out) {
  __shared__ __align__(16) ushort As[128 * 32];
  __shared__ __align__(16) ushort Bs[128 * 32];
  const int z = blockIdx.z;
  const int m0 = blockIdx.y * 128;
  const int n0 = blockIdx.x * 128;
  floatx4 acc[4][4];
  const floatx4 z4 = {0.f, 0.f, 0.f, 0.f};
#pragma unroll
  for (int i = 0; i < 4; ++i)
#pragma unroll
    for (int j = 0; j < 4; ++j) acc[i][j] = z4;

  mfma_gemm_core(Pb + (size_t)z * TDIM * TDIM + (size_t)m0 * TDIM,
                 vt + (size_t)z * DDIM * TDIM + (size_t)n0 * TDIM, TDIM, TDIM,
                 TDIM, As, Bs, acc);

  const int tid = threadIdx.x;
  const int wave = tid >> 6, lane = tid & 63;
  const int l15 = lane & 15, quad = lane >> 4;
  const int wm = wave >> 1, wn = wave & 1;
  float* O = out + (size_t)z * TDIM * DDIM;
#pragma unroll
  for (int i = 0; i < 4; ++i) {
    const int rbase = m0 + wm * 64 + i * 16 + quad * 4;
#pragma unroll
    for (int j = 0; j < 4; ++j) {
      const int col = n0 + wn * 64 + j * 16 + l15;
#pragma unroll
      for (int r = 0; r < 4; ++r)
        O[(size_t)(rbase + r) * DDIM + col] = acc[i][j][r];
    }
  }
}

// ---------------------------------------------------------------------------
extern "C" void kernel_launch(void* const* d_in, const int* in_sizes, int n_in,
                              void* d_out, int out_size, void* d_ws, size_t ws_size,
                              hipStream_t stream) {
  const float* x = (const float*)d_in[0];  // [4,2048,1024] fp32
  const float* W = (const float*)d_in[1];  // [3072,1024] fp32
  float* out = (float*)d_out;              // [4,2048,1024] fp32

  ushort* ws = (ushort*)d_ws;
  const size_t n_x = (size_t)NBATCH * TDIM * DDIM;  // 8.39M
  const size_t n_w = (size_t)3 * DDIM * DDIM;       // 3.15M
  ushort* xb = ws;                 // 16.8 MB
  ushort* wb = xb + n_x;           // 6.3 MB  (rows permuted q|k|v, q pre-scaled)
  ushort* qb = wb + n_w;           // 16.8 MB [b*t][d]
  ushort* kb = qb + n_x;           // 16.8 MB [b*t][d]
  ushort* vt = kb + n_x;           // 16.8 MB [b][d][t]
  ushort* Sb = vt + n_x;           // 33.5 MB [b][t][t] bf16 (scores -> P in place)

  convert_x<<<dim3((unsigned)(n_x / (256 * 4))), 256, 0, stream>>>(x, xb);
  convert_w<<<dim3(3 * DDIM), 256, 0, stream>>>(W, wb);
  qkv_gemm<<<dim3(3 * DDIM / 128, NBATCH * TDIM / 128), 256, 0, stream>>>(
      xb, wb, qb, kb, vt);
  score_gemm<<<dim3(TDIM / 128, TDIM / 128, NBATCH), 256, 0, stream>>>(qb, kb, Sb);
  softmax_rows<<<dim3(NBATCH * TDIM), 256, 0, stream>>>(Sb);
  pv_gemm<<<dim3(DDIM / 128, TDIM / 128, NBATCH), 256, 0, stream>>>(Sb, vt, out);
}

// Round 3
// 237.539 us; speedup vs baseline: 8.9263x; 1.2008x over previous
//
#include <hip/hip_runtime.h>
#include <math.h>

#define NBATCH 4
#define TDIM 2048
#define DDIM 1024

typedef __attribute__((ext_vector_type(8))) short short8;     // 8 bf16 MFMA frag
typedef __attribute__((ext_vector_type(4))) float floatx4;    // MFMA acc
typedef __attribute__((ext_vector_type(8))) unsigned short ushort8;
typedef __attribute__((ext_vector_type(4))) unsigned short ushort4v;

__device__ __forceinline__ unsigned short f2bf(float f) {
  unsigned int u = __float_as_uint(f);
  u += 0x7fffu + ((u >> 16) & 1u);   // round-to-nearest-even
  return (unsigned short)(u >> 16);
}
__device__ __forceinline__ float bf2f(unsigned short h) {
  return __uint_as_float(((unsigned int)h) << 16);
}

// async 16B global -> LDS (HW places lane i at lds_base + i*16)
__device__ __forceinline__ void gload_lds16(const ushort* g, ushort* l) {
  __builtin_amdgcn_global_load_lds(
      (const __attribute__((address_space(1))) void*)g,
      (__attribute__((address_space(3))) void*)l, 16, 0, 0);
}

// ---------------------------------------------------------------------------
// MFMA GEMM core, BK=64: C[128x128] block, NT (both operands K-contiguous bf16)
// C[m][n] += sum_k A[m][k]*B[n][k].  256 threads = 4 waves, wave (wm,wn) owns
// a 64x64 quadrant as 4x4 tiles of mfma_f32_16x16x32_bf16 (2 k-groups/iter).
//
// LDS: As/Bs [128 rows][64 k] bf16 = 16 KB each.  Row = 128 B = 8 chunks of
// 16 B.  XOR-8 swizzle: logical chunk c of row r lives at slot c ^ (r&7).
//  - staging (global_load_lds, lane l -> base + l*16): lane l covers row
//    8i + l/8, slot l&7, so it must FETCH source chunk (l&7) ^ ((l/8)&7) —
//    compatible with the DMA's fixed linear placement, no padding needed.
//  - reads: row stride 128 B => every row starts at bank 0; slot varies with
//    row&7 so 16 fragment rows spread over all 32 banks at 2 lanes/bank =
//    conflict-free (2-way is free per m136).
//  - slot algebra: for fragment row ar, ar&7 == l15&7 (t*16, w*64 are %8==0),
//    so the ds_read offset is one base + t*2048B immediate; k-group 1 is
//    base ^ 32 (slot^4 <=> offset^32 ushorts, no carries).
// ---------------------------------------------------------------------------
__device__ __forceinline__ void mfma_gemm_core(
    const ushort* __restrict__ Abase, const ushort* __restrict__ Bbase,
    int lda, int ldb, int K, ushort* As, ushort* Bs, floatx4 acc[4][4]) {
  const int tid = threadIdx.x;
  const int wave = tid >> 6;
  const int lane = tid & 63;
  const int l15 = lane & 15;
  const int quad = lane >> 4;
  const int wm = wave >> 1, wn = wave & 1;

  // staging: wave stages rows [32*wave, 32*wave+32) of A and of B,
  // 4 insts x 8 rows each.
  const int srow = wave * 32 + (lane >> 3);
  const int schunk = (lane & 7) ^ ((lane >> 3) & 7);
  const ushort* ag = Abase + (size_t)srow * lda + schunk * 8;
  const ushort* bg = Bbase + (size_t)srow * ldb + schunk * 8;
  ushort* al = As + wave * 32 * 64;
  ushort* bl = Bs + wave * 32 * 64;

  // fragment read bases (g=0); g=1 is ^32.  t adds 16*64 = 1024 ushorts.
  const int slot = quad ^ (l15 & 7);
  const int abase = (wm * 64 + l15) * 64 + slot * 8;
  const int bbase = (wn * 64 + l15) * 64 + slot * 8;

  for (int kt = 0; kt < K; kt += 64) {
#pragma unroll
    for (int i = 0; i < 4; ++i) {
      gload_lds16(ag + kt + (size_t)(8 * i) * lda, al + 8 * i * 64);
      gload_lds16(bg + kt + (size_t)(8 * i) * ldb, bl + 8 * i * 64);
    }
    __syncthreads();
#pragma unroll
    for (int g = 0; g < 2; ++g) {
      const int ab = abase ^ (g * 32);
      const int bb = bbase ^ (g * 32);
      short8 af[4], bfr[4];
#pragma unroll
      for (int t = 0; t < 4; ++t) {
        af[t] = *(const short8*)&As[ab + t * 1024];
        bfr[t] = *(const short8*)&Bs[bb + t * 1024];
      }
#pragma unroll
      for (int i = 0; i < 4; ++i)
#pragma unroll
        for (int j = 0; j < 4; ++j)
          acc[i][j] =
              __builtin_amdgcn_mfma_f32_16x16x32_bf16(af[i], bfr[j], acc[i][j], 0, 0, 0);
    }
    __syncthreads();
  }
}

// ---------------------------------------------------------------------------
// Fused converts: blocks [0,8192) convert x (1024 floats each); blocks
// [8192, 8192+3072) convert W row e -> permuted row (e%3)*1024 + e/3, with
// q-rows (e%3==0) pre-scaled by exact 1/32 (folds the 1/sqrt(d) score scale).
// ---------------------------------------------------------------------------
__global__ __launch_bounds__(256) void convert_xw(
    const float* __restrict__ x, const float* __restrict__ W,
    ushort* __restrict__ xb, ushort* __restrict__ wb) {
  const int bid = blockIdx.x;
  if (bid < 8192) {
    const size_t i = (size_t)bid * 256 + threadIdx.x;  // float4 index
    float4 v = reinterpret_cast<const float4*>(x)[i];
    ushort4v h = {f2bf(v.x), f2bf(v.y), f2bf(v.z), f2bf(v.w)};
    reinterpret_cast<ushort4v*>(xb)[i] = h;
  } else {
    const int e = bid - 8192;
    const int c = e % 3, ii = e / 3;
    const float scale = (c == 0) ? 0.03125f : 1.0f;
    const float4 v = reinterpret_cast<const float4*>(W + (size_t)e * DDIM)[threadIdx.x];
    ushort4v h = {f2bf(v.x * scale), f2bf(v.y * scale), f2bf(v.z * scale),
                  f2bf(v.w * scale)};
    reinterpret_cast<ushort4v*>(wb + (size_t)(c * DDIM + ii) * DDIM)[threadIdx.x] = h;
  }
}

// ---------------------------------------------------------------------------
// QKV: [8192 x 3072] = xb[8192x1024] * wb[3072x1024]^T.  wb rows permuted
// (q|k|v blocks) so each 128-col block is pure q, k or v.  q,k row-major;
// v transposed [b][d][t] for PV's NT.
// ---------------------------------------------------------------------------
__global__ __launch_bounds__(256, 3) void qkv_gemm(
    const ushort* __restrict__ xb, const ushort* __restrict__ wb,
    ushort* __restrict__ qb, ushort* __restrict__ kb, ushort* __restrict__ vt) {
  __shared__ __align__(16) ushort As[128 * 64];
  __shared__ __align__(16) ushort Bs[128 * 64];
  const int m0 = blockIdx.y * 128;
  const int n0 = blockIdx.x * 128;
  floatx4 acc[4][4];
  const floatx4 z4 = {0.f, 0.f, 0.f, 0.f};
#pragma unroll
  for (int i = 0; i < 4; ++i)
#pragma unroll
    for (int j = 0; j < 4; ++j) acc[i][j] = z4;

  mfma_gemm_core(xb + (size_t)m0 * DDIM, wb + (size_t)n0 * DDIM, DDIM, DDIM,
                 DDIM, As, Bs, acc);

  const int tid = threadIdx.x;
  const int wave = tid >> 6, lane = tid & 63;
  const int l15 = lane & 15, quad = lane >> 4;
  const int wm = wave >> 1, wn = wave & 1;

  if (n0 < 2 * DDIM) {
    ushort* dst = (n0 < DDIM) ? qb : kb;
    const int cb = (n0 < DDIM) ? n0 : n0 - DDIM;
#pragma unroll
    for (int i = 0; i < 4; ++i) {
      const int rbase = m0 + wm * 64 + i * 16 + quad * 4;
#pragma unroll
      for (int j = 0; j < 4; ++j) {
        const int col = cb + wn * 64 + j * 16 + l15;
#pragma unroll
        for (int r = 0; r < 4; ++r)
          dst[(size_t)(rbase + r) * DDIM + col] = f2bf(acc[i][j][r]);
      }
    }
  } else {
#pragma unroll
    for (int i = 0; i < 4; ++i) {
      const int row = m0 + wm * 64 + i * 16 + quad * 4;  // 4 consecutive t
      const int b = row >> 11, t = row & (TDIM - 1);
#pragma unroll
      for (int j = 0; j < 4; ++j) {
        const int d = (n0 - 2 * DDIM) + wn * 64 + j * 16 + l15;
        ushort4v pk = {f2bf(acc[i][j][0]), f2bf(acc[i][j][1]),
                       f2bf(acc[i][j][2]), f2bf(acc[i][j][3])};
        *reinterpret_cast<ushort4v*>(&vt[(size_t)((b << 10) + d) * TDIM + t]) = pk;
      }
    }
  }
}

// ---------------------------------------------------------------------------
// Scores: S[i][j] = q_scaled[i]·k[j] per batch (scale folded into q rows)
// ---------------------------------------------------------------------------
__global__ __launch_bounds__(256, 3) void score_gemm(
    const ushort* __restrict__ qb, const ushort* __restrict__ kb,
    ushort* __restrict__ Sb) {
  __shared__ __align__(16) ushort As[128 * 64];
  __shared__ __align__(16) ushort Bs[128 * 64];
  const int z = blockIdx.z;
  const int m0 = blockIdx.y * 128;
  const int n0 = blockIdx.x * 128;
  floatx4 acc[4][4];
  const floatx4 z4 = {0.f, 0.f, 0.f, 0.f};
#pragma unroll
  for (int i = 0; i < 4; ++i)
#pragma unroll
    for (int j = 0; j < 4; ++j) acc[i][j] = z4;

  mfma_gemm_core(qb + ((size_t)z * TDIM + m0) * DDIM,
                 kb + ((size_t)z * TDIM + n0) * DDIM, DDIM, DDIM, DDIM, As, Bs,
                 acc);

  const int tid = threadIdx.x;
  const int wave = tid >> 6, lane = tid & 63;
  const int l15 = lane & 15, quad = lane >> 4;
  const int wm = wave >> 1, wn = wave & 1;
  ushort* S = Sb + (size_t)z * TDIM * TDIM;
#pragma unroll
  for (int i = 0; i < 4; ++i) {
    const int rbase = m0 + wm * 64 + i * 16 + quad * 4;
#pragma unroll
    for (int j = 0; j < 4; ++j) {
      const int col = n0 + wn * 64 + j * 16 + l15;
#pragma unroll
      for (int r = 0; r < 4; ++r)
        S[(size_t)(rbase + r) * TDIM + col] = f2bf(acc[i][j][r]);
    }
  }
}

// ---------------------------------------------------------------------------
// Row softmax over bf16 scores, in place.
// ---------------------------------------------------------------------------
__global__ __launch_bounds__(256) void softmax_rows(ushort* __restrict__ Sb) {
  __shared__ float redm[4], reds[4];
  const int tid = threadIdx.x;
  ushort* p = Sb + (size_t)blockIdx.x * TDIM;
  ushort8 hv = *reinterpret_cast<const ushort8*>(&p[tid * 8]);
  float x[8];
#pragma unroll
  for (int e = 0; e < 8; ++e) x[e] = bf2f(hv[e]);

  float m = x[0];
#pragma unroll
  for (int e = 1; e < 8; ++e) m = fmaxf(m, x[e]);
#pragma unroll
  for (int off = 32; off > 0; off >>= 1) m = fmaxf(m, __shfl_down(m, off, 64));
  const int wave = tid >> 6, lane = tid & 63;
  if (lane == 0) redm[wave] = m;
  __syncthreads();
  m = fmaxf(fmaxf(redm[0], redm[1]), fmaxf(redm[2], redm[3]));

  float s = 0.f;
#pragma unroll
  for (int e = 0; e < 8; ++e) {
    x[e] = __expf(x[e] - m);
    s += x[e];
  }
#pragma unroll
  for (int off = 32; off > 0; off >>= 1) s += __shfl_down(s, off, 64);
  if (lane == 0) reds[wave] = s;
  __syncthreads();
  s = reds[0] + reds[1] + reds[2] + reds[3];
  const float inv = 1.0f / s;
#pragma unroll
  for (int e = 0; e < 8; ++e) hv[e] = f2bf(x[e] * inv);
  *reinterpret_cast<ushort8*>(&p[tid * 8]) = hv;
}

// ---------------------------------------------------------------------------
// PV: out[t][d] = sum_j P[t][j] * vt[d][j]  (NT, both K-contiguous bf16)
// ---------------------------------------------------------------------------
__global__ __launch_bounds__(256, 3) void pv_gemm(
    const ushort* __restrict__ Pb, const ushort* __restrict__ vt,
    float* __restrict__ out) {
  __shared__ __align__(16) ushort As[128 * 64];
  __shared__ __align__(16) ushort Bs[128 * 64];
  const int z = blockIdx.z;
  const int m0 = blockIdx.y * 128;
  const int n0 = blockIdx.x * 128;
  floatx4 acc[4][4];
  const floatx4 z4 = {0.f, 0.f, 0.f, 0.f};
#pragma unroll
  for (int i = 0; i < 4; ++i)
#pragma unroll
    for (int j = 0; j < 4; ++j) acc[i][j] = z4;

  mfma_gemm_core(Pb + (size_t)z * TDIM * TDIM + (size_t)m0 * TDIM,
                 vt + (size_t)z * DDIM * TDIM + (size_t)n0 * TDIM, TDIM, TDIM,
                 TDIM, As, Bs, acc);

  const int tid = threadIdx.x;
  const int wave = tid >> 6, lane = tid & 63;
  const int l15 = lane & 15, quad = lane >> 4;
  const int wm = wave >> 1, wn = wave & 1;
  float* O = out + (size_t)z * TDIM * DDIM;
#pragma unroll
  for (int i = 0; i < 4; ++i) {
    const int rbase = m0 + wm * 64 + i * 16 + quad * 4;
#pragma unroll
    for (int j = 0; j < 4; ++j) {
      const int col = n0 + wn * 64 + j * 16 + l15;
#pragma unroll
      for (int r = 0; r < 4; ++r)
        O[(size_t)(rbase + r) * DDIM + col] = acc[i][j][r];
    }
  }
}

// ---------------------------------------------------------------------------
extern "C" void kernel_launch(void* const* d_in, const int* in_sizes, int n_in,
                              void* d_out, int out_size, void* d_ws, size_t ws_size,
                              hipStream_t stream) {
  const float* x = (const float*)d_in[0];  // [4,2048,1024] fp32
  const float* W = (const float*)d_in[1];  // [3072,1024] fp32
  float* out = (float*)d_out;              // [4,2048,1024] fp32

  ushort* ws = (ushort*)d_ws;
  const size_t n_x = (size_t)NBATCH * TDIM * DDIM;  // 8.39M
  const size_t n_w = (size_t)3 * DDIM * DDIM;       // 3.15M
  ushort* xb = ws;        // 16.8 MB
  ushort* wb = xb + n_x;  // 6.3 MB (rows permuted q|k|v, q pre-scaled 1/32)
  ushort* qb = wb + n_w;  // 16.8 MB [b*t][d]
  ushort* kb = qb + n_x;  // 16.8 MB [b*t][d]
  ushort* vt = kb + n_x;  // 16.8 MB [b][d][t]
  ushort* Sb = vt + n_x;  // 33.5 MB [b][t][t] bf16 (scores -> P in place)

  convert_xw<<<dim3(8192 + 3 * DDIM), 256, 0, stream>>>(x, W, xb, wb);
  qkv_gemm<<<dim3(3 * DDIM / 128, NBATCH * TDIM / 128), 256, 0, stream>>>(
      xb, wb, qb, kb, vt);
  score_gemm<<<dim3(TDIM / 128, TDIM / 128, NBATCH), 256, 0, stream>>>(qb, kb, Sb);
  softmax_rows<<<dim3(NBATCH * TDIM), 256, 0, stream>>>(Sb);
  pv_gemm<<<dim3(DDIM / 128, TDIM / 128, NBATCH), 256, 0, stream>>>(Sb, vt, out);
}